// Round 26
// baseline (60.906 us; speedup 1.0000x reference)
//
#include <hip/hip_runtime.h>
#include <hip/hip_bf16.h>

#define N_NODES 50000
#define N_EDGES 800000
#define NBK 196          // coarse buckets of 256 dst nodes (dst>>8); 196*256 = 50176
#define BCAP 40          // per-bucket LDS stage capacity in bin path (lambda=21, +4sigma)
#define CAP  4864        // fixed bucket region size: mean 4082 + 12 sigma (64)
#define GEMM_BLOCKS 391  // ceil(50000/128)

typedef __attribute__((ext_vector_type(8))) short bf16x8;   // MFMA A/B frag
typedef __attribute__((ext_vector_type(4))) float f32x4;    // MFMA C/D frag

__device__ __forceinline__ float blo(unsigned u) { return __uint_as_float(u << 16); }
__device__ __forceinline__ float bhi(unsigned u) { return __uint_as_float(u & 0xffff0000u); }
__device__ __forceinline__ unsigned short f2bu(float f) {
    __hip_bfloat16 hb = __float2bfloat16(f);   // RNE
    return *(unsigned short*)&hb;
}
__device__ __forceinline__ unsigned pk2(float a, float b) {
    return (unsigned)f2bu(a) | ((unsigned)f2bu(b) << 16);
}

// ---------------- k1bin: FUSED GEMM (blocks 0-390) + edge binning (391-586) -----
// (R24-proven) bin depends only on gcur=0 (memset before), not on the GEMM ->
// both run concurrently in one dispatch. LDS union 52.2KB, 3 blocks/CU.
__global__ void __launch_bounds__(256, 3)
k1bin(const float* __restrict__ x, const float* __restrict__ state,
      const float* __restrict__ W, const float* __restrict__ a_src,
      const float* __restrict__ a_dst, const int* __restrict__ ei,
      unsigned short* __restrict__ hf2, float* __restrict__ s_src4,
      float* __restrict__ s_dst4, int* __restrict__ gcur, int* __restrict__ recs) {
    __shared__ union ULds {
        struct { unsigned short alds[128 * 136]; unsigned short wlds[64 * 136]; } g;
        struct { int cnt[NBK]; int stage[NBK][BCAP]; } b;
    } u;
    int tid = threadIdx.x;

    if (blockIdx.x >= GEMM_BLOCKS) {
        // ---------------- bin path (196 blocks x 4096 edges) -------------------
        int bb = blockIdx.x - GEMM_BLOCKS;
        for (int i = tid; i < NBK; i += 256) u.b.cnt[i] = 0;
        __syncthreads();
        int e0 = bb * 4096;
#pragma unroll
        for (int k = 0; k < 4; ++k) {
            int e = e0 + k * 1024 + tid * 4;
            if (e < N_EDGES) {
                int4 sv = *(const int4*)(ei + e);
                int4 dv = *(const int4*)(ei + N_EDGES + e);
                int ss[4] = {sv.x, sv.y, sv.z, sv.w};
                int dd[4] = {dv.x, dv.y, dv.z, dv.w};
#pragma unroll
                for (int j = 0; j < 4; ++j) {
                    int b = dd[j] >> 8;
                    int rec = ss[j] | ((dd[j] & 255) << 16);
                    int p = atomicAdd(&u.b.cnt[b], 1);
                    if (p < BCAP) u.b.stage[b][p] = rec;
                    else {                     // rare overflow: direct store
                        int g = atomicAdd(&gcur[b], 1);
                        recs[b * CAP + g] = rec;
                    }
                }
            }
        }
        __syncthreads();
        for (int b = tid; b < NBK; b += 256) {
            int nb = min(u.b.cnt[b], BCAP);
            if (nb > 0) {
                int g = atomicAdd(&gcur[b], nb);
                int d0 = b * CAP + g;
                for (int i = 0; i < nb; ++i) recs[d0 + i] = u.b.stage[b][i];
            }
        }
        return;
    }

    // ---------------- GEMM path (128-node tiles) -------------------------------
    unsigned short* alds = u.g.alds;
    unsigned short* wlds = u.g.wlds;
    int nb = blockIdx.x * 128;

    const float4* x4  = (const float4*)x;
    const float4* st4 = (const float4*)state;
    const float4* W4  = (const float4*)W;
    for (int idx = tid; idx < 4096; idx += 256) {       // A: 128 rows x 32 quads
        int row = idx >> 5, qc = idx & 31;
        int n = nb + row;
        float4 v = make_float4(0.f, 0.f, 0.f, 0.f);
        if (n < N_NODES)
            v = (qc < 16) ? x4[(long)n * 16 + qc] : st4[(long)n * 16 + (qc - 16)];
        unsigned* ap = (unsigned*)&alds[row * 136 + qc * 4];
        ap[0] = pk2(v.x, v.y);
        ap[1] = pk2(v.z, v.w);
    }
    for (int idx = tid; idx < 2048; idx += 256) {       // W: 64 rows x 32 quads
        int row = idx >> 5, qc = idx & 31;
        float4 wv = W4[idx];
        unsigned* wp = (unsigned*)&wlds[row * 136 + qc * 4];
        wp[0] = pk2(wv.x, wv.y);
        wp[1] = pk2(wv.z, wv.w);
    }
    __syncthreads();

    int lane = tid & 63;
    int w = tid >> 6;                          // wave w: node rows w*32..w*32+31
    int lrow = lane & 15, lq = lane >> 4;

    f32x4 acc[2][4];
#pragma unroll
    for (int rt = 0; rt < 2; ++rt)
#pragma unroll
        for (int c = 0; c < 4; ++c) acc[rt][c] = (f32x4){0.f, 0.f, 0.f, 0.f};

#pragma unroll
    for (int kc = 0; kc < 4; ++kc) {
        bf16x8 af0 = *(const bf16x8*)&alds[(w * 32 + lrow) * 136 + kc * 32 + lq * 8];
        bf16x8 af1 = *(const bf16x8*)&alds[(w * 32 + 16 + lrow) * 136 + kc * 32 + lq * 8];
#pragma unroll
        for (int c = 0; c < 4; ++c) {
            bf16x8 bf = *(const bf16x8*)&wlds[(c * 16 + lrow) * 136 + kc * 32 + lq * 8];
            acc[0][c] = __builtin_amdgcn_mfma_f32_16x16x32_bf16(af0, bf, acc[0][c], 0, 0, 0);
            acc[1][c] = __builtin_amdgcn_mfma_f32_16x16x32_bf16(af1, bf, acc[1][c], 0, 0, 0);
        }
    }
    __syncthreads();

    // stage fp32 h tile [128][68]; C layout col=lane&15, row=(lane>>4)*4+reg
    float* hst = (float*)alds;
#pragma unroll
    for (int rt = 0; rt < 2; ++rt)
#pragma unroll
        for (int r = 0; r < 4; ++r) {
            int nl = w * 32 + rt * 16 + lq * 4 + r;
#pragma unroll
            for (int c = 0; c < 4; ++c)
                hst[nl * 68 + c * 16 + lrow] = acc[rt][c][r];
        }
    __syncthreads();

    // coalesced outputs: thread t = (node t>>2 and +64, head t&3); h as bf16
#pragma unroll
    for (int g = 0; g < 2; ++g) {
        int node = (tid >> 2) + g * 64, chunk = tid & 3;
        int n = nb + node;
        if (n < N_NODES) {
            const float* hp = &hst[node * 68 + chunk * 16];
            float hv[16];
            float vs = 0.f, vd = 0.f;
#pragma unroll
            for (int i = 0; i < 16; ++i) {
                hv[i] = hp[i];
                vs = fmaf(hv[i], a_src[chunk * 16 + i], vs);
                vd = fmaf(hv[i], a_dst[chunk * 16 + i], vd);
            }
            unsigned pk[8];
#pragma unroll
            for (int j = 0; j < 8; ++j) pk[j] = pk2(hv[2 * j], hv[2 * j + 1]);
            uint4* dst = (uint4*)(hf2 + (long)n * 64 + chunk * 16);
            dst[0] = make_uint4(pk[0], pk[1], pk[2], pk[3]);
            dst[1] = make_uint4(pk[4], pk[5], pk[6], pk[7]);
            s_src4[(long)n * 4 + chunk] = vs;
            s_dst4[(long)n * 4 + chunk] = vd;
        }
    }
}

// ---------------- k_sort: within-bucket counting sort, 512 threads (R23) --------
__global__ void __launch_bounds__(512)
k_sort(const int* __restrict__ recs, const int* __restrict__ gcur,
       int* __restrict__ recs2, int* __restrict__ off, int* __restrict__ deg) {
    __shared__ int cnt[256];
    __shared__ int pos[256];
    __shared__ int wsum[4];
    int tid = threadIdx.x, b = blockIdx.x;
    if (tid < 256) cnt[tid] = 0;
    __syncthreads();
    int base = b * CAP, cntb = gcur[b];
    for (int i = tid; i < cntb; i += 512)
        atomicAdd(&cnt[(recs[base + i] >> 16) & 255], 1);
    __syncthreads();
    int lane = tid & 63, wid = tid >> 6;
    int v = (tid < 256) ? cnt[tid] : 0;
    int inc = v;
#pragma unroll
    for (int s = 1; s < 64; s <<= 1) {
        int t = __shfl_up(inc, s);
        if (lane >= s) inc += t;
    }
    if (lane == 63 && wid < 4) wsum[wid] = inc;
    __syncthreads();
    if (tid == 0) {
        int s = 0;
#pragma unroll
        for (int w = 0; w < 4; ++w) { int t = wsum[w]; wsum[w] = s; s += t; }
    }
    __syncthreads();
    if (tid < 256) {
        int excl = wsum[wid] + inc - v;
        pos[tid] = excl;
        int n = b * 256 + tid;
        if (n < N_NODES) { off[n] = base + excl; deg[n] = v; }
    }
    __syncthreads();
    for (int i = tid; i < cntb; i += 512) {
        int r = recs[base + i];
        int p = atomicAdd(&pos[(r >> 16) & 255], 1);
        recs2[base + p] = r & 0xFFFF;          // store src only
    }
}

// ---------------- k_agg: direct per-slot csr loads (no shfl in the chain) -------
// R25 lesson trail: k_agg resists slot-count/ILP/precision/layout attacks. Last
// untested chain link: the DS-pipe shfl broadcast. The 8 lanes of a slot want
// the SAME csr word -> the memory path broadcasts same-address loads natively,
// and the node's <=256B csr range is L1-hot after step 0. This removes the
// svl pre-load + guard and the ~60cy DS hop from every step. OOB index loads
// stay inside the recs2 allocation; garbage is mask-clamped to 0 before any h2
// address is formed.
__global__ void k_agg(const int* __restrict__ off, const int* __restrict__ deg,
                      const int* __restrict__ csr, const float* __restrict__ s_src4,
                      const float* __restrict__ s_dst4,
                      const unsigned short* __restrict__ h2, float* __restrict__ out) {
    int wave = threadIdx.x >> 6, lane = threadIdx.x & 63;
    int n = blockIdx.x * 4 + wave;
    if (n >= N_NODES) return;
    int q = lane >> 3, d = lane & 7, hh = d >> 1;   // slot q, dim-octet d, head hh
    int b = off[n], nE = deg[n];
    float sdh = s_dst4[(long)n * 4 + hh];

    float den = 0.f;
    float a0 = 0, a1 = 0, a2 = 0, a3 = 0, a4 = 0, a5 = 0, a6 = 0, a7 = 0;
    for (int j = 0; j < nE; j += 16) {
        int j0 = j + q, j1 = j + 8 + q;
        bool v0 = (j0 < nE), v1 = (j1 < nE);
        // same-address-per-slot loads -> HW broadcast; L1-hot after step 0.
        int r0 = csr[b + j0];                  // in-allocation even past nE
        int r1 = csr[b + j1];
        int s0 = v0 ? r0 : 0;                  // clamp BEFORE address formation
        int s1 = v1 ? r1 : 0;
        float m0 = v0 ? 1.f : 0.f;
        float m1 = v1 ? 1.f : 0.f;
        // issue all gathers up front (4 independent streams)
        float l0 = s_src4[s0 * 4 + hh];
        float l1 = s_src4[s1 * 4 + hh];
        uint4 A = *(const uint4*)(h2 + (long)s0 * 64 + 8 * d);  // 16B: 8 bf16
        uint4 B = *(const uint4*)(h2 + (long)s1 * 64 + 8 * d);
        l0 += sdh; l1 += sdh;
        float e0 = m0 * __expf(fmaxf(l0, 0.2f * l0));
        float e1 = m1 * __expf(fmaxf(l1, 0.2f * l1));
        den += e0 + e1;
        a0 = fmaf(e0, blo(A.x), a0); a1 = fmaf(e0, bhi(A.x), a1);
        a2 = fmaf(e0, blo(A.y), a2); a3 = fmaf(e0, bhi(A.y), a3);
        a4 = fmaf(e0, blo(A.z), a4); a5 = fmaf(e0, bhi(A.z), a5);
        a6 = fmaf(e0, blo(A.w), a6); a7 = fmaf(e0, bhi(A.w), a7);
        a0 = fmaf(e1, blo(B.x), a0); a1 = fmaf(e1, bhi(B.x), a1);
        a2 = fmaf(e1, blo(B.y), a2); a3 = fmaf(e1, bhi(B.y), a3);
        a4 = fmaf(e1, blo(B.z), a4); a5 = fmaf(e1, bhi(B.z), a5);
        a6 = fmaf(e1, blo(B.w), a6); a7 = fmaf(e1, bhi(B.w), a7);
    }
#pragma unroll
    for (int o2 = 8; o2 < 64; o2 <<= 1) {          // reduce across the 8 slots
        den += __shfl_xor(den, o2);
        a0 += __shfl_xor(a0, o2);
        a1 += __shfl_xor(a1, o2);
        a2 += __shfl_xor(a2, o2);
        a3 += __shfl_xor(a3, o2);
        a4 += __shfl_xor(a4, o2);
        a5 += __shfl_xor(a5, o2);
        a6 += __shfl_xor(a6, o2);
        a7 += __shfl_xor(a7, o2);
    }

    if (q == 0) {                              // 8 lanes, dims 8d..8d+7
        uint4 hr = *(const uint4*)(h2 + (long)n * 64 + 8 * d);
        float inv = 1.0f / (den + 1e-12f);
        float o0 = a0 * inv + blo(hr.x), o1 = a1 * inv + bhi(hr.x);
        float o2 = a2 * inv + blo(hr.y), o3 = a3 * inv + bhi(hr.y);
        float o4 = a4 * inv + blo(hr.z), o5 = a5 * inv + bhi(hr.z);
        float o6 = a6 * inv + blo(hr.w), o7 = a7 * inv + bhi(hr.w);
        o0 = (o0 > 0.f) ? o0 : __expf(o0) - 1.f;
        o1 = (o1 > 0.f) ? o1 : __expf(o1) - 1.f;
        o2 = (o2 > 0.f) ? o2 : __expf(o2) - 1.f;
        o3 = (o3 > 0.f) ? o3 : __expf(o3) - 1.f;
        o4 = (o4 > 0.f) ? o4 : __expf(o4) - 1.f;
        o5 = (o5 > 0.f) ? o5 : __expf(o5) - 1.f;
        o6 = (o6 > 0.f) ? o6 : __expf(o6) - 1.f;
        o7 = (o7 > 0.f) ? o7 : __expf(o7) - 1.f;
        float* op = &out[(long)n * 64 + 8 * d];
        *(float4*)(op + 0) = make_float4(o0, o1, o2, o3);
        *(float4*)(op + 4) = make_float4(o4, o5, o6, o7);
    }
}

extern "C" void kernel_launch(void* const* d_in, const int* in_sizes, int n_in,
                              void* d_out, int out_size, void* d_ws, size_t ws_size,
                              hipStream_t stream) {
    const float* x      = (const float*)d_in[0];
    const float* state  = (const float*)d_in[1];
    const int*   ei     = (const int*)d_in[2];     // [2, E]
    // d_in[3] = edge_weight (ignored)
    const float* W      = (const float*)d_in[4];   // [64,128]
    const float* a_src  = (const float*)d_in[5];
    const float* a_dst  = (const float*)d_in[6];

    float* out = (float*)d_out;

    // ws layout: hf2 [N*64] u16 | s_src4 [N*4] f32 | s_dst4 [N*4] | gcur[256] |
    //            off[N] | deg[N] | recs [196*CAP] | recs2 [196*CAP]   (~15 MB)
    unsigned short* hf2 = (unsigned short*)d_ws;
    float* s_src4 = (float*)(hf2 + (long)N_NODES * 64);
    float* s_dst4 = s_src4 + (long)N_NODES * 4;
    int*   gcur   = (int*)(s_dst4 + (long)N_NODES * 4);
    int*   off    = gcur + 256;
    int*   deg    = off + N_NODES;
    int*   recs   = deg + N_NODES;
    int*   recs2  = recs + (long)NBK * CAP;

    // 4 dispatches: memset(gcur) -> fused k1bin -> sort -> agg
    hipMemsetAsync(gcur, 0, NBK * sizeof(int), stream);
    k1bin<<<GEMM_BLOCKS + NBK, 256, 0, stream>>>(x, state, W, a_src, a_dst, ei,
                                                 hf2, s_src4, s_dst4, gcur, recs);
    k_sort<<<NBK, 512, 0, stream>>>(recs, gcur, recs2, off, deg);
    k_agg<<<(N_NODES + 3) / 4, 256, 0, stream>>>(off, deg, recs2, s_src4, s_dst4, hf2, out);
}

// Round 27
// 59.078 us; speedup vs baseline: 1.0309x; 1.0309x over previous
//
#include <hip/hip_runtime.h>
#include <hip/hip_bf16.h>

#define N_NODES 50000
#define N_EDGES 800000
#define NBK 196          // coarse buckets of 256 dst nodes (dst>>8); 196*256 = 50176
#define BCAP 40          // per-bucket LDS stage capacity in bin path (lambda=21, +4sigma)
#define CAP  4864        // fixed bucket region size: mean 4082 + 12 sigma (64)
#define GEMM_BLOCKS 391  // ceil(50000/128)

typedef __attribute__((ext_vector_type(8))) short bf16x8;   // MFMA A/B frag
typedef __attribute__((ext_vector_type(4))) float f32x4;    // MFMA C/D frag

__device__ __forceinline__ float blo(unsigned u) { return __uint_as_float(u << 16); }
__device__ __forceinline__ float bhi(unsigned u) { return __uint_as_float(u & 0xffff0000u); }
__device__ __forceinline__ unsigned short f2bu(float f) {
    __hip_bfloat16 hb = __float2bfloat16(f);   // RNE
    return *(unsigned short*)&hb;
}
__device__ __forceinline__ unsigned pk2(float a, float b) {
    return (unsigned)f2bu(a) | ((unsigned)f2bu(b) << 16);
}

// ---------------- k1bin: FUSED GEMM (blocks 0-390) + edge binning (391-586) -----
// (R24-proven) bin depends only on gcur=0 (memset before), not on the GEMM ->
// both run concurrently in one dispatch. LDS union 52.2KB, 3 blocks/CU.
__global__ void __launch_bounds__(256, 3)
k1bin(const float* __restrict__ x, const float* __restrict__ state,
      const float* __restrict__ W, const float* __restrict__ a_src,
      const float* __restrict__ a_dst, const int* __restrict__ ei,
      unsigned short* __restrict__ hf2, float* __restrict__ s_src4,
      float* __restrict__ s_dst4, int* __restrict__ gcur, int* __restrict__ recs) {
    __shared__ union ULds {
        struct { unsigned short alds[128 * 136]; unsigned short wlds[64 * 136]; } g;
        struct { int cnt[NBK]; int stage[NBK][BCAP]; } b;
    } u;
    int tid = threadIdx.x;

    if (blockIdx.x >= GEMM_BLOCKS) {
        // ---------------- bin path (196 blocks x 4096 edges) -------------------
        int bb = blockIdx.x - GEMM_BLOCKS;
        for (int i = tid; i < NBK; i += 256) u.b.cnt[i] = 0;
        __syncthreads();
        int e0 = bb * 4096;
#pragma unroll
        for (int k = 0; k < 4; ++k) {
            int e = e0 + k * 1024 + tid * 4;
            if (e < N_EDGES) {
                int4 sv = *(const int4*)(ei + e);
                int4 dv = *(const int4*)(ei + N_EDGES + e);
                int ss[4] = {sv.x, sv.y, sv.z, sv.w};
                int dd[4] = {dv.x, dv.y, dv.z, dv.w};
#pragma unroll
                for (int j = 0; j < 4; ++j) {
                    int b = dd[j] >> 8;
                    int rec = ss[j] | ((dd[j] & 255) << 16);
                    int p = atomicAdd(&u.b.cnt[b], 1);
                    if (p < BCAP) u.b.stage[b][p] = rec;
                    else {                     // rare overflow: direct store
                        int g = atomicAdd(&gcur[b], 1);
                        recs[b * CAP + g] = rec;
                    }
                }
            }
        }
        __syncthreads();
        for (int b = tid; b < NBK; b += 256) {
            int nb = min(u.b.cnt[b], BCAP);
            if (nb > 0) {
                int g = atomicAdd(&gcur[b], nb);
                int d0 = b * CAP + g;
                for (int i = 0; i < nb; ++i) recs[d0 + i] = u.b.stage[b][i];
            }
        }
        return;
    }

    // ---------------- GEMM path (128-node tiles) -------------------------------
    unsigned short* alds = u.g.alds;
    unsigned short* wlds = u.g.wlds;
    int nb = blockIdx.x * 128;

    const float4* x4  = (const float4*)x;
    const float4* st4 = (const float4*)state;
    const float4* W4  = (const float4*)W;
    for (int idx = tid; idx < 4096; idx += 256) {       // A: 128 rows x 32 quads
        int row = idx >> 5, qc = idx & 31;
        int n = nb + row;
        float4 v = make_float4(0.f, 0.f, 0.f, 0.f);
        if (n < N_NODES)
            v = (qc < 16) ? x4[(long)n * 16 + qc] : st4[(long)n * 16 + (qc - 16)];
        unsigned* ap = (unsigned*)&alds[row * 136 + qc * 4];
        ap[0] = pk2(v.x, v.y);
        ap[1] = pk2(v.z, v.w);
    }
    for (int idx = tid; idx < 2048; idx += 256) {       // W: 64 rows x 32 quads
        int row = idx >> 5, qc = idx & 31;
        float4 wv = W4[idx];
        unsigned* wp = (unsigned*)&wlds[row * 136 + qc * 4];
        wp[0] = pk2(wv.x, wv.y);
        wp[1] = pk2(wv.z, wv.w);
    }
    __syncthreads();

    int lane = tid & 63;
    int w = tid >> 6;                          // wave w: node rows w*32..w*32+31
    int lrow = lane & 15, lq = lane >> 4;

    f32x4 acc[2][4];
#pragma unroll
    for (int rt = 0; rt < 2; ++rt)
#pragma unroll
        for (int c = 0; c < 4; ++c) acc[rt][c] = (f32x4){0.f, 0.f, 0.f, 0.f};

#pragma unroll
    for (int kc = 0; kc < 4; ++kc) {
        bf16x8 af0 = *(const bf16x8*)&alds[(w * 32 + lrow) * 136 + kc * 32 + lq * 8];
        bf16x8 af1 = *(const bf16x8*)&alds[(w * 32 + 16 + lrow) * 136 + kc * 32 + lq * 8];
#pragma unroll
        for (int c = 0; c < 4; ++c) {
            bf16x8 bf = *(const bf16x8*)&wlds[(c * 16 + lrow) * 136 + kc * 32 + lq * 8];
            acc[0][c] = __builtin_amdgcn_mfma_f32_16x16x32_bf16(af0, bf, acc[0][c], 0, 0, 0);
            acc[1][c] = __builtin_amdgcn_mfma_f32_16x16x32_bf16(af1, bf, acc[1][c], 0, 0, 0);
        }
    }
    __syncthreads();

    // stage fp32 h tile [128][68]; C layout col=lane&15, row=(lane>>4)*4+reg
    float* hst = (float*)alds;
#pragma unroll
    for (int rt = 0; rt < 2; ++rt)
#pragma unroll
        for (int r = 0; r < 4; ++r) {
            int nl = w * 32 + rt * 16 + lq * 4 + r;
#pragma unroll
            for (int c = 0; c < 4; ++c)
                hst[nl * 68 + c * 16 + lrow] = acc[rt][c][r];
        }
    __syncthreads();

    // coalesced outputs: thread t = (node t>>2 and +64, head t&3); h as bf16
#pragma unroll
    for (int g = 0; g < 2; ++g) {
        int node = (tid >> 2) + g * 64, chunk = tid & 3;
        int n = nb + node;
        if (n < N_NODES) {
            const float* hp = &hst[node * 68 + chunk * 16];
            float hv[16];
            float vs = 0.f, vd = 0.f;
#pragma unroll
            for (int i = 0; i < 16; ++i) {
                hv[i] = hp[i];
                vs = fmaf(hv[i], a_src[chunk * 16 + i], vs);
                vd = fmaf(hv[i], a_dst[chunk * 16 + i], vd);
            }
            unsigned pk[8];
#pragma unroll
            for (int j = 0; j < 8; ++j) pk[j] = pk2(hv[2 * j], hv[2 * j + 1]);
            uint4* dst = (uint4*)(hf2 + (long)n * 64 + chunk * 16);
            dst[0] = make_uint4(pk[0], pk[1], pk[2], pk[3]);
            dst[1] = make_uint4(pk[4], pk[5], pk[6], pk[7]);
            s_src4[(long)n * 4 + chunk] = vs;
            s_dst4[(long)n * 4 + chunk] = vd;
        }
    }
}

// ---------------- k_sort: within-bucket counting sort, 512 threads (R23) --------
__global__ void __launch_bounds__(512)
k_sort(const int* __restrict__ recs, const int* __restrict__ gcur,
       int* __restrict__ recs2, int* __restrict__ off, int* __restrict__ deg) {
    __shared__ int cnt[256];
    __shared__ int pos[256];
    __shared__ int wsum[4];
    int tid = threadIdx.x, b = blockIdx.x;
    if (tid < 256) cnt[tid] = 0;
    __syncthreads();
    int base = b * CAP, cntb = gcur[b];
    for (int i = tid; i < cntb; i += 512)
        atomicAdd(&cnt[(recs[base + i] >> 16) & 255], 1);
    __syncthreads();
    int lane = tid & 63, wid = tid >> 6;
    int v = (tid < 256) ? cnt[tid] : 0;
    int inc = v;
#pragma unroll
    for (int s = 1; s < 64; s <<= 1) {
        int t = __shfl_up(inc, s);
        if (lane >= s) inc += t;
    }
    if (lane == 63 && wid < 4) wsum[wid] = inc;
    __syncthreads();
    if (tid == 0) {
        int s = 0;
#pragma unroll
        for (int w = 0; w < 4; ++w) { int t = wsum[w]; wsum[w] = s; s += t; }
    }
    __syncthreads();
    if (tid < 256) {
        int excl = wsum[wid] + inc - v;
        pos[tid] = excl;
        int n = b * 256 + tid;
        if (n < N_NODES) { off[n] = base + excl; deg[n] = v; }
    }
    __syncthreads();
    for (int i = tid; i < cntb; i += 512) {
        int r = recs[base + i];
        int p = atomicAdd(&pos[(r >> 16) & 255], 1);
        recs2[base + p] = r & 0xFFFF;          // store src only
    }
}

// ---------------- k_agg: 8-slot, bf16 h, 2-edge ILP + single-chunk fast path ----
// R25-proven best. R26 confirmed the shfl broadcast was NOT the bottleneck; the
// per-edge step is bound by the random h2/s_src gather latency (structural).
__global__ void k_agg(const int* __restrict__ off, const int* __restrict__ deg,
                      const int* __restrict__ csr, const float* __restrict__ s_src4,
                      const float* __restrict__ s_dst4,
                      const unsigned short* __restrict__ h2, float* __restrict__ out) {
    int wave = threadIdx.x >> 6, lane = threadIdx.x & 63;
    int n = blockIdx.x * 4 + wave;
    if (n >= N_NODES) return;
    int q = lane >> 3, d = lane & 7, hh = d >> 1;   // slot q, dim-octet d, head hh
    int b = off[n], nE = deg[n];
    float sdh = s_dst4[(long)n * 4 + hh];

    float den = 0.f;
    float a0 = 0, a1 = 0, a2 = 0, a3 = 0, a4 = 0, a5 = 0, a6 = 0, a7 = 0;

    if (nE <= 64) {                            // fast path: single chunk
        int svl = (lane < nE) ? csr[b + lane] : 0;
        for (int j = 0; j < nE; j += 16) {
            int j0 = j + q, j1 = j + 8 + q;    // both <= 63
            float m0 = (j0 < nE) ? 1.f : 0.f;
            float m1 = (j1 < nE) ? 1.f : 0.f;
            int s0 = __shfl(svl, j0);
            int s1 = __shfl(svl, j1);
            float l0 = s_src4[s0 * 4 + hh];
            float l1 = s_src4[s1 * 4 + hh];
            uint4 A = *(const uint4*)(h2 + (long)s0 * 64 + 8 * d);
            uint4 B = *(const uint4*)(h2 + (long)s1 * 64 + 8 * d);
            l0 += sdh; l1 += sdh;
            float e0 = m0 * __expf(fmaxf(l0, 0.2f * l0));
            float e1 = m1 * __expf(fmaxf(l1, 0.2f * l1));
            den += e0 + e1;
            a0 = fmaf(e0, blo(A.x), a0); a1 = fmaf(e0, bhi(A.x), a1);
            a2 = fmaf(e0, blo(A.y), a2); a3 = fmaf(e0, bhi(A.y), a3);
            a4 = fmaf(e0, blo(A.z), a4); a5 = fmaf(e0, bhi(A.z), a5);
            a6 = fmaf(e0, blo(A.w), a6); a7 = fmaf(e0, bhi(A.w), a7);
            a0 = fmaf(e1, blo(B.x), a0); a1 = fmaf(e1, bhi(B.x), a1);
            a2 = fmaf(e1, blo(B.y), a2); a3 = fmaf(e1, bhi(B.y), a3);
            a4 = fmaf(e1, blo(B.z), a4); a5 = fmaf(e1, bhi(B.z), a5);
            a6 = fmaf(e1, blo(B.w), a6); a7 = fmaf(e1, bhi(B.w), a7);
        }
    } else {                                   // general path (any degree)
        for (int c = 0; c < nE; c += 64) {
            int jn = min(64, nE - c);
            int svl = (lane < jn) ? csr[b + c + lane] : 0;
            for (int j = 0; j < jn; j += 16) {
                int j0 = j + q, j1 = j + 8 + q;
                float m0 = (j0 < jn) ? 1.f : 0.f;
                float m1 = (j1 < jn) ? 1.f : 0.f;
                int s0 = __shfl(svl, j0);
                int s1 = __shfl(svl, j1);
                float l0 = s_src4[s0 * 4 + hh];
                float l1 = s_src4[s1 * 4 + hh];
                uint4 A = *(const uint4*)(h2 + (long)s0 * 64 + 8 * d);
                uint4 B = *(const uint4*)(h2 + (long)s1 * 64 + 8 * d);
                l0 += sdh; l1 += sdh;
                float e0 = m0 * __expf(fmaxf(l0, 0.2f * l0));
                float e1 = m1 * __expf(fmaxf(l1, 0.2f * l1));
                den += e0 + e1;
                a0 = fmaf(e0, blo(A.x), a0); a1 = fmaf(e0, bhi(A.x), a1);
                a2 = fmaf(e0, blo(A.y), a2); a3 = fmaf(e0, bhi(A.y), a3);
                a4 = fmaf(e0, blo(A.z), a4); a5 = fmaf(e0, bhi(A.z), a5);
                a6 = fmaf(e0, blo(A.w), a6); a7 = fmaf(e0, bhi(A.w), a7);
                a0 = fmaf(e1, blo(B.x), a0); a1 = fmaf(e1, bhi(B.x), a1);
                a2 = fmaf(e1, blo(B.y), a2); a3 = fmaf(e1, bhi(B.y), a3);
                a4 = fmaf(e1, blo(B.z), a4); a5 = fmaf(e1, bhi(B.z), a5);
                a6 = fmaf(e1, blo(B.w), a6); a7 = fmaf(e1, bhi(B.w), a7);
            }
        }
    }
#pragma unroll
    for (int o2 = 8; o2 < 64; o2 <<= 1) {          // reduce across the 8 slots
        den += __shfl_xor(den, o2);
        a0 += __shfl_xor(a0, o2);
        a1 += __shfl_xor(a1, o2);
        a2 += __shfl_xor(a2, o2);
        a3 += __shfl_xor(a3, o2);
        a4 += __shfl_xor(a4, o2);
        a5 += __shfl_xor(a5, o2);
        a6 += __shfl_xor(a6, o2);
        a7 += __shfl_xor(a7, o2);
    }

    if (q == 0) {                              // 8 lanes, dims 8d..8d+7
        uint4 hr = *(const uint4*)(h2 + (long)n * 64 + 8 * d);
        float inv = 1.0f / (den + 1e-12f);
        float o0 = a0 * inv + blo(hr.x), o1 = a1 * inv + bhi(hr.x);
        float o2 = a2 * inv + blo(hr.y), o3 = a3 * inv + bhi(hr.y);
        float o4 = a4 * inv + blo(hr.z), o5 = a5 * inv + bhi(hr.z);
        float o6 = a6 * inv + blo(hr.w), o7 = a7 * inv + bhi(hr.w);
        o0 = (o0 > 0.f) ? o0 : __expf(o0) - 1.f;
        o1 = (o1 > 0.f) ? o1 : __expf(o1) - 1.f;
        o2 = (o2 > 0.f) ? o2 : __expf(o2) - 1.f;
        o3 = (o3 > 0.f) ? o3 : __expf(o3) - 1.f;
        o4 = (o4 > 0.f) ? o4 : __expf(o4) - 1.f;
        o5 = (o5 > 0.f) ? o5 : __expf(o5) - 1.f;
        o6 = (o6 > 0.f) ? o6 : __expf(o6) - 1.f;
        o7 = (o7 > 0.f) ? o7 : __expf(o7) - 1.f;
        float* op = &out[(long)n * 64 + 8 * d];
        *(float4*)(op + 0) = make_float4(o0, o1, o2, o3);
        *(float4*)(op + 4) = make_float4(o4, o5, o6, o7);
    }
}

extern "C" void kernel_launch(void* const* d_in, const int* in_sizes, int n_in,
                              void* d_out, int out_size, void* d_ws, size_t ws_size,
                              hipStream_t stream) {
    const float* x      = (const float*)d_in[0];
    const float* state  = (const float*)d_in[1];
    const int*   ei     = (const int*)d_in[2];     // [2, E]
    // d_in[3] = edge_weight (ignored)
    const float* W      = (const float*)d_in[4];   // [64,128]
    const float* a_src  = (const float*)d_in[5];
    const float* a_dst  = (const float*)d_in[6];

    float* out = (float*)d_out;

    // ws layout: hf2 [N*64] u16 | s_src4 [N*4] f32 | s_dst4 [N*4] | gcur[256] |
    //            off[N] | deg[N] | recs [196*CAP] | recs2 [196*CAP]   (~15 MB)
    unsigned short* hf2 = (unsigned short*)d_ws;
    float* s_src4 = (float*)(hf2 + (long)N_NODES * 64);
    float* s_dst4 = s_src4 + (long)N_NODES * 4;
    int*   gcur   = (int*)(s_dst4 + (long)N_NODES * 4);
    int*   off    = gcur + 256;
    int*   deg    = off + N_NODES;
    int*   recs   = deg + N_NODES;
    int*   recs2  = recs + (long)NBK * CAP;

    // 4 dispatches: memset(gcur) -> fused k1bin -> sort -> agg
    hipMemsetAsync(gcur, 0, NBK * sizeof(int), stream);
    k1bin<<<GEMM_BLOCKS + NBK, 256, 0, stream>>>(x, state, W, a_src, a_dst, ei,
                                                 hf2, s_src4, s_dst4, gcur, recs);
    k_sort<<<NBK, 512, 0, stream>>>(recs, gcur, recs2, off, deg);
    k_agg<<<(N_NODES + 3) / 4, 256, 0, stream>>>(off, deg, recs2, s_src4, s_dst4, hf2, out);
}